// Round 8
// baseline (154.242 us; speedup 1.0000x reference)
//
#include <hip/hip_runtime.h>

// ---------------------------------------------------------------------------
// Q_DenseLayer: BN-fold int8 affine -> ReLU -> per-tensor 8b quant ->
// int8 3x3 conv (MFMA i32_16x16x64_i8) -> per-tensor 8b requant.
// Shapes: x[32,512,32,32] f32, W[128,512,3,3] f32, out y[32,128,32,32] + s_out.
//
// R16: shrink pipe VOLUMES instead of re-scheduling fixed ones (R13/R14/R15
// all plateaued at k_conv ~26us; LDS was the largest pipe at ~3450 cyc/iter/
// CU). Wave = 4 rows x 16 w x 32 co (acc[4][2]): B-reuse 2->4 halves LDS
// ds_read traffic per MFMA; A-reuse 6->8 via kh-chain CSE (A[6][3] window).
// Block = 8 waves (512 thr) = rq(2) x wh(2) x nh(2) = 8 rows x 32 w x 64 co;
// grid 256 XCD-swizzled = 1 block/CU, 2 waves/SIMD. Per CU/iter: LDS 1730,
// MFMA 2940 (critical), TA ~2000 cyc -> sum 7000 vs R13's 9000.
// Dbuf B (2x36KB LDS), one __syncthreads/iter, per-kh B batches with
// one-batch lookahead, setprio around MFMA clusters. ~200 VGPR @ (512,2).
// Layouts: x2 [b][h][ci8][cq4][w'34][16B], wq [tap][ci][cq4][co128][16B].
// Fixed ~95us harness work (ws poison + d_in restore) outside our control.
// ---------------------------------------------------------------------------

typedef int v4i __attribute__((ext_vector_type(4)));

// workspace byte offsets
#define WS_A1    64        // 512 f: A1_c = w_int*bn_sf/s_in
#define WS_B1    2112      // 512 f: B1_c = b_int*bn_sf
#define WS_WSC   4160      // 128 f
#define WS_XMX   4672      // 512 f: per-channel max(x)
#define WS_XMN   6720      // 512 f: per-channel min(x)
#define WS_WQ    8768      // 589824 i8: [tap][ci][cq][co128][16]
#define WS_X2    598592    // 17825792 u8: [b][h][ci][cq][w'34][16]
#define WS_ZROW  18424384  // 17408 u8 zero row
// ws_f[3] = s_act (k_xquant blk0), ws_u[1] = absmax(y) bits

__device__ __forceinline__ float wave_max(float m) {
#pragma unroll
    for (int off = 32; off; off >>= 1) m = fmaxf(m, __shfl_xor(m, off));
    return m;
}

// async global->LDS, 16B per lane: per-lane gsrc, wave-uniform LDS base
__device__ __forceinline__ void stage16(const char* g, char* s, int lane) {
#if defined(__has_builtin) && __has_builtin(__builtin_amdgcn_global_load_lds)
    __builtin_amdgcn_global_load_lds(
        (const __attribute__((address_space(1))) void*)g,
        (__attribute__((address_space(3))) void*)s, 16, 0, 0);
#else
    *(v4i*)(s + lane * 16) = *(const v4i*)g;
#endif
}

// ---- kernel 1: fused prep ---------------------------------------------------
// blocks 0..511:   per-channel x max/min (block c owns channel c)
// blocks 512..639: conv-weight quant (co = bid-512)
// block 640:       BN fold -> A1/B1, zero y-absmax
__global__ __launch_bounds__(512) void k_prep(
    const float* __restrict__ gamma, const float* __restrict__ beta,
    const float* __restrict__ mean,  const float* __restrict__ var,
    const float* __restrict__ asf,   const float* __restrict__ cw,
    const float4* __restrict__ x4,
    float* ws_f, unsigned* ws_u, float* __restrict__ wsc,
    signed char* __restrict__ wq) {
    int t = threadIdx.x;
    int bid = blockIdx.x;
    __shared__ float red[16];
    if (bid < 512) {
        int c = bid;
        float mx = -3.4e38f, mn = 3.4e38f;
#pragma unroll
        for (int r = 0; r < 16; ++r) {
            int bbb = r * 2 + (t >> 8);
            float4 v = x4[((size_t)(bbb * 512 + c)) * 256 + (t & 255)];
            mx = fmaxf(mx, fmaxf(fmaxf(v.x, v.y), fmaxf(v.z, v.w)));
            mn = fminf(mn, fminf(fminf(v.x, v.y), fminf(v.z, v.w)));
        }
        mx = wave_max(mx);
        mn = -wave_max(-mn);
        if ((t & 63) == 0) { red[t >> 6] = mx; red[8 + (t >> 6)] = mn; }
        __syncthreads();
        if (t == 0) {
            float M = red[0], N = red[8];
#pragma unroll
            for (int i = 1; i < 8; ++i) { M = fmaxf(M, red[i]); N = fminf(N, red[8 + i]); }
            ws_f[WS_XMX / 4 + c] = M;
            ws_f[WS_XMN / 4 + c] = N;
        }
    } else if (bid < 640) {
        int co = bid - 512;
        const float* w = cw + (size_t)co * 4608;
        float m = 0.f;
        for (int j = t; j < 4608; j += 512) m = fmaxf(m, fabsf(w[j]));
        m = wave_max(m);
        if ((t & 63) == 0) red[t >> 6] = m;
        __syncthreads();
        float mall = red[0];
#pragma unroll
        for (int i = 1; i < 8; ++i) mall = fmaxf(mall, red[i]);
        float sc = mall / 127.0f;
        if (t == 0) wsc[co] = sc;
        int ci = t >> 6, cq = (t >> 4) & 3, cb = t & 15;
#pragma unroll
        for (int tap = 0; tap < 9; ++tap) {
            float q = fminf(fmaxf(rintf(w[t * 9 + tap] / sc), -128.f), 127.f);
            wq[(((size_t)(tap * 8 + ci) * 4 + cq) * 128 + co) * 16 + cb] = (signed char)q;
        }
    } else {
        float wbn = gamma[t] / sqrtf(var[t] + 1e-5f);
        float bbn = beta[t] - mean[t] * wbn;
        float m = wave_max(fabsf(wbn));
        if ((t & 63) == 0) red[t >> 6] = m;
        __syncthreads();
        float mall = red[0];
#pragma unroll
        for (int i = 1; i < 8; ++i) mall = fmaxf(mall, red[i]);
        float ws_bn = mall / 127.0f;
        float s_in  = asf[0];
        float bn_sf = ws_bn * s_in;
        float wint  = fminf(fmaxf(rintf(wbn / ws_bn), -128.f), 127.f);
        float bint  = rintf(bbn / bn_sf);
        ws_f[WS_A1 / 4 + t] = wint * bn_sf / s_in;  // x1 = fmaf(x, A1, B1)
        ws_f[WS_B1 / 4 + t] = bint * bn_sf;
        if (t == 0) ws_u[1] = 0u;  // absmax(y) bits
    }
}

// ---- kernel 2: quantize x to int8 [ci][cq][w'][16] halo layout -------------
__global__ __launch_bounds__(256) void k_xquant(
    const float4* __restrict__ x4, float* __restrict__ ws_f,
    unsigned* __restrict__ x2u, unsigned* __restrict__ zrowu) {
    int bb = 31 - (blockIdx.x >> 5), h = blockIdx.x & 31;
    const float* A1 = ws_f + WS_A1 / 4;
    const float* B1 = ws_f + WS_B1 / 4;
    const float* XMX = ws_f + WS_XMX / 4;
    const float* XMN = ws_f + WS_XMN / 4;
    int t = threadIdx.x;

    // s_act from per-channel stats (exact: fma monotone in x, relu clamp >=0)
    __shared__ float sred[4];
    float cand = 0.f;
#pragma unroll
    for (int c0 = 0; c0 < 512; c0 += 256) {
        int c = c0 + t;
        float A = A1[c], B = B1[c];
        cand = fmaxf(cand, fmaxf(fmaf(XMX[c], A, B), fmaf(XMN[c], A, B)));
    }
    cand = wave_max(cand);
    if ((t & 63) == 0) sred[t >> 6] = cand;
    __syncthreads();
    float xm = fmaxf(fmaxf(sred[0], sred[1]), fmaxf(sred[2], sred[3]));
    float inv_sact = 127.0f / xm;
    if (blockIdx.x == 0 && t == 0) ws_f[3] = xm / 127.0f;  // s_act for k_conv

    size_t rowd = (size_t)(bb * 32 + h) * 4352;  // dwords per (b,h) row
    // zero halo columns w'=0,33
    {
        int p = t >> 3, side = (t >> 2) & 1, d = t & 3;
        x2u[rowd + (p * 34 + side * 33) * 4 + d] = 0u;
    }
    if (blockIdx.x < 17) {
        int idx = blockIdx.x * 256 + t;
        if (idx < 4352) zrowu[idx] = 0u;
    }

    __shared__ unsigned lds[512 * 9];  // [c][w4(8)] packed bytes, +1 pad

#pragma unroll
    for (int it = 0; it < 16; ++it) {
        int idx = it * 256 + t;
        int c = idx >> 3, f4 = idx & 7;
        float4 v = x4[((size_t)bb * 512 + c) * 256 + h * 8 + f4];
        float A = A1[c] * inv_sact, B = B1[c] * inv_sact;
        unsigned q0 = (unsigned)(int)fminf(rintf(fmaxf(fmaf(v.x, A, B), 0.f)), 127.f);
        unsigned q1 = (unsigned)(int)fminf(rintf(fmaxf(fmaf(v.y, A, B), 0.f)), 127.f);
        unsigned q2 = (unsigned)(int)fminf(rintf(fmaxf(fmaf(v.z, A, B), 0.f)), 127.f);
        unsigned q3 = (unsigned)(int)fminf(rintf(fmaxf(fmaf(v.w, A, B), 0.f)), 127.f);
        lds[c * 9 + f4] = q0 | (q1 << 8) | (q2 << 16) | (q3 << 24);
    }
    __syncthreads();

#pragma unroll
    for (int it = 0; it < 4; ++it) {
        int p = it * 8 + (t >> 5);   // 0..31 = ci*4+cq
        int s = (t >> 2) & 7;        // w4 group
        int k = t & 3;               // w = s*4+k, w' = w+1
        unsigned L[16];
#pragma unroll
        for (int j = 0; j < 16; ++j) L[j] = lds[(p * 16 + j) * 9 + s];
        uint4 o;
        unsigned* op = (unsigned*)&o;
#pragma unroll
        for (int d = 0; d < 4; ++d)
            op[d] = ((L[4 * d] >> (8 * k)) & 255u) |
                    (((L[4 * d + 1] >> (8 * k)) & 255u) << 8) |
                    (((L[4 * d + 2] >> (8 * k)) & 255u) << 16) |
                    (((L[4 * d + 3] >> (8 * k)) & 255u) << 24);
        *(uint4*)(x2u + rowd + (size_t)(p * 34 + s * 4 + 1 + k) * 4) = o;
    }
}

// ---- kernel 3: int8 3x3 conv, 4-row waves (B-reuse 4), dbuf B --------------
// block = 8 waves (512 thr) = rq(2) x wh(2) x nh(2) -> 8 rows x 32 w x 64 co;
// wave = 4 rows x 16 w x 32 co, acc[4][2] (r = row, nt = co-16-group).
// Per K-iter per wave: 18 A-loads (6 in-rows x 3 kw, kh-chain CSE, reuse 8),
// 18 B ds_reads (9 taps x 2 nt, reuse 4 -- HALF of R12-R15's LDS traffic),
// 72 MFMA in 3 per-kh clusters (setprio), stage 4-5 gload_lds chunks of the
// next 36KB B tile. One __syncthreads/iter. Grid 256 XCD-swizzled = 1
// block/CU, 2 waves/SIMD. LDS 2x36KB dbuf.
__global__ __launch_bounds__(512, 2) void k_conv(
    const unsigned char* __restrict__ x2, const unsigned char* __restrict__ zrow,
    const signed char* __restrict__ wq,
    const float* __restrict__ wsc, const float* __restrict__ ws_f,
    unsigned* __restrict__ amaxy, float* __restrict__ y) {
    __shared__ char ldsb[73728];
    int t = threadIdx.x;
    int lane = t & 63, wv = t >> 6;
    int nh = wv & 1;            // co 32-half
    int wh = (wv >> 1) & 1;     // w 16-half
    int rq = wv >> 2;           // row-quad
    int m = lane & 15, quad = lane >> 4;

    int bid = blockIdx.x;
    int tile = (bid & 7) * 32 + (bid >> 3);  // XCD swizzle, 32 tiles/XCD
    int ch = tile & 1;                        // co 0..63 / 64..127
    int rg = (tile >> 1) & 3;                 // row-group of 8
    int bb = tile >> 3;
    int co0 = ch * 64;
    int h0 = rg * 8 + rq * 4;                 // wave's first output row

    const unsigned char* xb = x2 + (size_t)bb * (32 * 17408);
    const v4i* rpt[6];                        // in-rows h0-1 .. h0+4
#pragma unroll
    for (int j = 0; j < 6; ++j) {
        int row = h0 - 1 + j;
        rpt[j] = (const v4i*)(((unsigned)row < 32u) ? (xb + (size_t)row * 17408) : zrow);
    }

    v4i acc[4][2];
#pragma unroll
    for (int i = 0; i < 4; ++i)
#pragma unroll
        for (int j = 0; j < 2; ++j) acc[i][j] = (v4i){0, 0, 0, 0};

    int abase = quad * 34 + m + wh * 16;  // [cq=quad][w'=m+wh*16] in v4i units

    // stage one 36KB B tile (36 x 1KB chunks over 8 waves: 4-5 each)
    auto stage_ci = [&](int cig, int buf) {
#pragma unroll
        for (int i = 0; i < 5; ++i) {
            int c = i * 8 + wv;
            if (c < 36) {
                int tap = c >> 2, cq = c & 3;
                const char* g = (const char*)wq +
                    ((((size_t)(tap * 8 + cig) * 4 + cq) * 128 + co0) * 16) + lane * 16;
                stage16(g, ldsb + buf * 36864 + (c << 10), lane);
            }
        }
    };

    stage_ci(0, 0);
    __syncthreads();

#pragma unroll
    for (int ci = 0; ci < 8; ++ci) {
        const v4i* bv = (const v4i*)(ldsb + (ci & 1) * 36864);

        // A window: 6 in-rows x 3 kw (72 VGPR), feeds all 3 kh clusters
        v4i A[6][3];
#pragma unroll
        for (int j = 0; j < 6; ++j)
#pragma unroll
            for (int kw = 0; kw < 3; ++kw)
                A[j][kw] = rpt[j][ci * 136 + abase + kw];

        auto load_Bk = [&](v4i(&B)[3][2], int kh) {
#pragma unroll
            for (int kw = 0; kw < 3; ++kw)
#pragma unroll
                for (int nt = 0; nt < 2; ++nt)
                    B[kw][nt] = bv[((kh * 3 + kw) * 4 + quad) * 64 + nh * 32 + nt * 16 + m];
        };
        // one kh cluster: 3 kw x (4 rows x 2 nt) = 24 MFMA; same-acc distance 8
        auto mfma_kh = [&](const v4i(&Ar0)[3], const v4i(&Ar1)[3],
                           const v4i(&Ar2)[3], const v4i(&Ar3)[3],
                           const v4i(&B)[3][2]) {
            __builtin_amdgcn_s_setprio(1);
#pragma unroll
            for (int kw = 0; kw < 3; ++kw) {
                acc[0][0] = __builtin_amdgcn_mfma_i32_16x16x64_i8(Ar0[kw], B[kw][0], acc[0][0], 0, 0, 0);
                acc[0][1] = __builtin_amdgcn_mfma_i32_16x16x64_i8(Ar0[kw], B[kw][1], acc[0][1], 0, 0, 0);
                acc[1][0] = __builtin_amdgcn_mfma_i32_16x16x64_i8(Ar1[kw], B[kw][0], acc[1][0], 0, 0, 0);
                acc[1][1] = __builtin_amdgcn_mfma_i32_16x16x64_i8(Ar1[kw], B[kw][1], acc[1][1], 0, 0, 0);
                acc[2][0] = __builtin_amdgcn_mfma_i32_16x16x64_i8(Ar2[kw], B[kw][0], acc[2][0], 0, 0, 0);
                acc[2][1] = __builtin_amdgcn_mfma_i32_16x16x64_i8(Ar2[kw], B[kw][1], acc[2][1], 0, 0, 0);
                acc[3][0] = __builtin_amdgcn_mfma_i32_16x16x64_i8(Ar3[kw], B[kw][0], acc[3][0], 0, 0, 0);
                acc[3][1] = __builtin_amdgcn_mfma_i32_16x16x64_i8(Ar3[kw], B[kw][1], acc[3][1], 0, 0, 0);
            }
            __builtin_amdgcn_s_setprio(0);
        };

        v4i B0[3][2], B1[3][2], B2[3][2];
        load_Bk(B0, 0);
        load_Bk(B1, 1);
        if (ci < 7) stage_ci(ci + 1, (ci + 1) & 1);  // stages drain at barrier,
                                                     // covered by 72 MFMAs
        mfma_kh(A[0], A[1], A[2], A[3], B0);
        load_Bk(B2, 2);
        mfma_kh(A[1], A[2], A[3], A[4], B1);
        mfma_kh(A[2], A[3], A[4], A[5], B2);

        __syncthreads();  // cur-buf reads done + next-buf stages complete
    }

    // epilogue: C layout col(lane&15)=co, row(quad*4+reg)=w-within-half.
    // y unquantized; track block absmax -> one atomicMax per block.
    float s_act = ws_f[3];
    float mx = 0.f;
#pragma unroll
    for (int nt = 0; nt < 2; ++nt) {
        int co = co0 + nh * 32 + nt * 16 + m;
        float sf = s_act * wsc[co];
#pragma unroll
        for (int r = 0; r < 4; ++r) {
            int row = h0 + r;
            float* yb = y + ((size_t)(bb * 128 + co)) * 1024 + row * 32 + wh * 16;
            float4 vv;
            vv.x = (float)acc[r][nt][0] * sf;
            vv.y = (float)acc[r][nt][1] * sf;
            vv.z = (float)acc[r][nt][2] * sf;
            vv.w = (float)acc[r][nt][3] * sf;
            *(float4*)(yb + quad * 4) = vv;
            mx = fmaxf(mx, fmaxf(fmaxf(fabsf(vv.x), fabsf(vv.y)),
                                 fmaxf(fabsf(vv.z), fabsf(vv.w))));
        }
    }
    mx = wave_max(mx);
    if (lane == 0) ((float*)ldsb)[wv] = mx;   // loop ended with __syncthreads
    __syncthreads();
    if (t == 0) {
        float* r = (float*)ldsb;
        float M = r[0];
#pragma unroll
        for (int i = 1; i < 8; ++i) M = fmaxf(M, r[i]);
        atomicMax(amaxy, __float_as_uint(M));
    }
}

// ---- kernel 4: final requant in place + write s_out -----------------------
__global__ __launch_bounds__(256) void k_yquant(float* __restrict__ yout,
                                                const unsigned* __restrict__ ws_u) {
    float s_out = __uint_as_float(ws_u[1]) / 127.0f;
    float4* y4 = (float4*)yout;
    int stride = gridDim.x * blockDim.x;
    for (int i = blockIdx.x * blockDim.x + threadIdx.x; i < 1048576; i += stride) {
        float4 v = y4[i];
        v.x = fminf(fmaxf(rintf(v.x / s_out), -128.f), 127.f) * s_out;
        v.y = fminf(fmaxf(rintf(v.y / s_out), -128.f), 127.f) * s_out;
        v.z = fminf(fmaxf(rintf(v.z / s_out), -128.f), 127.f) * s_out;
        v.w = fminf(fmaxf(rintf(v.w / s_out), -128.f), 127.f) * s_out;
        y4[i] = v;
    }
    if (blockIdx.x == 0 && threadIdx.x == 0) yout[4194304] = s_out;
}

extern "C" void kernel_launch(void* const* d_in, const int* in_sizes, int n_in,
                              void* d_out, int out_size, void* d_ws, size_t ws_size,
                              hipStream_t stream) {
    const float* x     = (const float*)d_in[0];
    const float* asf   = (const float*)d_in[1];
    const float* gamma = (const float*)d_in[2];
    const float* beta  = (const float*)d_in[3];
    const float* mean  = (const float*)d_in[4];
    const float* var   = (const float*)d_in[5];
    const float* cw    = (const float*)d_in[6];

    float*    ws_f = (float*)d_ws;
    unsigned* ws_u = (unsigned*)d_ws;
    signed char*   wq   = (signed char*)d_ws + WS_WQ;
    unsigned char* x2   = (unsigned char*)d_ws + WS_X2;
    unsigned char* zrow = (unsigned char*)d_ws + WS_ZROW;
    float* y = (float*)d_out;

    k_prep<<<641, 512, 0, stream>>>(gamma, beta, mean, var, asf, cw,
                                    (const float4*)x, ws_f, ws_u,
                                    ws_f + WS_WSC / 4, wq);
    k_xquant<<<1024, 256, 0, stream>>>((const float4*)x, ws_f,
                                       (unsigned*)x2, (unsigned*)zrow);
    k_conv<<<256, 512, 0, stream>>>(x2, zrow, wq, ws_f + WS_WSC / 4,
                                    ws_f, ws_u + 1, y);
    k_yquant<<<1024, 256, 0, stream>>>(y, ws_u);
}

// Round 9
// 151.528 us; speedup vs baseline: 1.0179x; 1.0179x over previous
//
#include <hip/hip_runtime.h>

// ---------------------------------------------------------------------------
// Q_DenseLayer: BN-fold int8 affine -> ReLU -> per-tensor 8b quant ->
// int8 3x3 conv (MFMA i32_16x16x64_i8) -> per-tensor 8b requant.
// Shapes: x[32,512,32,32] f32, W[128,512,3,3] f32, out y[32,128,32,32] + s_out.
//
// R17: REVERT to R14 (best measured: 151.6us) after the k_conv exploration
// closed out. Plateau evidence: k_conv = 26 +/- 1us across occupancy
// 1/2/4 blk/CU (R16/R12/R11), A-reuse 2..8, B-reuse 2..4, three barrier
// disciplines (syncthreads / issue-ordered / counted-vmcnt raw barriers,
// R12/R14/R15), reg blocking 52->230 VGPR, setprio, sched_barrier. 2 blk/CU
// variants all ~26us; 1 blk/CU regresses (no cross-block barrier cover).
// Remaining budget: k_prep ~10.6 (cold x read, HBM floor), k_xquant ~9
// (L3-warm x re-read + x2 write; two passes algorithmically required for
// exact per-tensor s_act), k_conv ~26 (plateau), k_yquant ~6 (y round-trip
// floor; in-conv fusion costs more than it saves -- R9/R10), ~95us fixed
// harness work (ws poison + d_in restore) outside kernel control.
//
// R14 structure: per K-iter issue order (vmcnt retires in issue order):
//   A-loads x12 -> B0,B1 ds_reads -> stage16 x9 (next buf) ->
//   MFMA kh0 (A-wait leaves stages in flight) -> B2 ds_reads ->
//   MFMA kh1 -> MFMA kh2 -> ONE __syncthreads.
// dbuf B (2x36KB LDS, 2 blk/CU), wave = 2 rows x 16 w x 64 co (A-reuse 4),
// A[4][3] hoist (kh-chain CSE), B0/B1/B2 kh-pipeline, setprio clusters,
// grid 512 XCD-swizzled, no K-split.
// Layouts: x2 [b][h][ci8][cq4][w'34][16B], wq [tap][ci][cq4][co128][16B].
// ---------------------------------------------------------------------------

typedef int v4i __attribute__((ext_vector_type(4)));

// workspace byte offsets
#define WS_A1    64        // 512 f: A1_c = w_int*bn_sf/s_in
#define WS_B1    2112      // 512 f: B1_c = b_int*bn_sf
#define WS_WSC   4160      // 128 f
#define WS_XMX   4672      // 512 f: per-channel max(x)
#define WS_XMN   6720      // 512 f: per-channel min(x)
#define WS_WQ    8768      // 589824 i8: [tap][ci][cq][co128][16]
#define WS_X2    598592    // 17825792 u8: [b][h][ci][cq][w'34][16]
#define WS_ZROW  18424384  // 17408 u8 zero row
// ws_f[3] = s_act (k_xquant blk0), ws_u[1] = absmax(y) bits

__device__ __forceinline__ float wave_max(float m) {
#pragma unroll
    for (int off = 32; off; off >>= 1) m = fmaxf(m, __shfl_xor(m, off));
    return m;
}

// async global->LDS, 16B per lane: per-lane gsrc, wave-uniform LDS base
__device__ __forceinline__ void stage16(const char* g, char* s, int lane) {
#if defined(__has_builtin) && __has_builtin(__builtin_amdgcn_global_load_lds)
    __builtin_amdgcn_global_load_lds(
        (const __attribute__((address_space(1))) void*)g,
        (__attribute__((address_space(3))) void*)s, 16, 0, 0);
#else
    *(v4i*)(s + lane * 16) = *(const v4i*)g;
#endif
}

// ---- kernel 1: fused prep ---------------------------------------------------
// blocks 0..511:   per-channel x max/min (block c owns channel c)
// blocks 512..639: conv-weight quant (co = bid-512)
// block 640:       BN fold -> A1/B1, zero y-absmax
__global__ __launch_bounds__(512) void k_prep(
    const float* __restrict__ gamma, const float* __restrict__ beta,
    const float* __restrict__ mean,  const float* __restrict__ var,
    const float* __restrict__ asf,   const float* __restrict__ cw,
    const float4* __restrict__ x4,
    float* ws_f, unsigned* ws_u, float* __restrict__ wsc,
    signed char* __restrict__ wq) {
    int t = threadIdx.x;
    int bid = blockIdx.x;
    __shared__ float red[16];
    if (bid < 512) {
        int c = bid;
        float mx = -3.4e38f, mn = 3.4e38f;
#pragma unroll
        for (int r = 0; r < 16; ++r) {
            int bbb = r * 2 + (t >> 8);
            float4 v = x4[((size_t)(bbb * 512 + c)) * 256 + (t & 255)];
            mx = fmaxf(mx, fmaxf(fmaxf(v.x, v.y), fmaxf(v.z, v.w)));
            mn = fminf(mn, fminf(fminf(v.x, v.y), fminf(v.z, v.w)));
        }
        mx = wave_max(mx);
        mn = -wave_max(-mn);
        if ((t & 63) == 0) { red[t >> 6] = mx; red[8 + (t >> 6)] = mn; }
        __syncthreads();
        if (t == 0) {
            float M = red[0], N = red[8];
#pragma unroll
            for (int i = 1; i < 8; ++i) { M = fmaxf(M, red[i]); N = fminf(N, red[8 + i]); }
            ws_f[WS_XMX / 4 + c] = M;
            ws_f[WS_XMN / 4 + c] = N;
        }
    } else if (bid < 640) {
        int co = bid - 512;
        const float* w = cw + (size_t)co * 4608;
        float m = 0.f;
        for (int j = t; j < 4608; j += 512) m = fmaxf(m, fabsf(w[j]));
        m = wave_max(m);
        if ((t & 63) == 0) red[t >> 6] = m;
        __syncthreads();
        float mall = red[0];
#pragma unroll
        for (int i = 1; i < 8; ++i) mall = fmaxf(mall, red[i]);
        float sc = mall / 127.0f;
        if (t == 0) wsc[co] = sc;
        int ci = t >> 6, cq = (t >> 4) & 3, cb = t & 15;
#pragma unroll
        for (int tap = 0; tap < 9; ++tap) {
            float q = fminf(fmaxf(rintf(w[t * 9 + tap] / sc), -128.f), 127.f);
            wq[(((size_t)(tap * 8 + ci) * 4 + cq) * 128 + co) * 16 + cb] = (signed char)q;
        }
    } else {
        float wbn = gamma[t] / sqrtf(var[t] + 1e-5f);
        float bbn = beta[t] - mean[t] * wbn;
        float m = wave_max(fabsf(wbn));
        if ((t & 63) == 0) red[t >> 6] = m;
        __syncthreads();
        float mall = red[0];
#pragma unroll
        for (int i = 1; i < 8; ++i) mall = fmaxf(mall, red[i]);
        float ws_bn = mall / 127.0f;
        float s_in  = asf[0];
        float bn_sf = ws_bn * s_in;
        float wint  = fminf(fmaxf(rintf(wbn / ws_bn), -128.f), 127.f);
        float bint  = rintf(bbn / bn_sf);
        ws_f[WS_A1 / 4 + t] = wint * bn_sf / s_in;  // x1 = fmaf(x, A1, B1)
        ws_f[WS_B1 / 4 + t] = bint * bn_sf;
        if (t == 0) ws_u[1] = 0u;  // absmax(y) bits
    }
}

// ---- kernel 2: quantize x to int8 [ci][cq][w'][16] halo layout -------------
__global__ __launch_bounds__(256) void k_xquant(
    const float4* __restrict__ x4, float* __restrict__ ws_f,
    unsigned* __restrict__ x2u, unsigned* __restrict__ zrowu) {
    int bb = 31 - (blockIdx.x >> 5), h = blockIdx.x & 31;
    const float* A1 = ws_f + WS_A1 / 4;
    const float* B1 = ws_f + WS_B1 / 4;
    const float* XMX = ws_f + WS_XMX / 4;
    const float* XMN = ws_f + WS_XMN / 4;
    int t = threadIdx.x;

    // s_act from per-channel stats (exact: fma monotone in x, relu clamp >=0)
    __shared__ float sred[4];
    float cand = 0.f;
#pragma unroll
    for (int c0 = 0; c0 < 512; c0 += 256) {
        int c = c0 + t;
        float A = A1[c], B = B1[c];
        cand = fmaxf(cand, fmaxf(fmaf(XMX[c], A, B), fmaf(XMN[c], A, B)));
    }
    cand = wave_max(cand);
    if ((t & 63) == 0) sred[t >> 6] = cand;
    __syncthreads();
    float xm = fmaxf(fmaxf(sred[0], sred[1]), fmaxf(sred[2], sred[3]));
    float inv_sact = 127.0f / xm;
    if (blockIdx.x == 0 && t == 0) ws_f[3] = xm / 127.0f;  // s_act for k_conv

    size_t rowd = (size_t)(bb * 32 + h) * 4352;  // dwords per (b,h) row
    // zero halo columns w'=0,33
    {
        int p = t >> 3, side = (t >> 2) & 1, d = t & 3;
        x2u[rowd + (p * 34 + side * 33) * 4 + d] = 0u;
    }
    if (blockIdx.x < 17) {
        int idx = blockIdx.x * 256 + t;
        if (idx < 4352) zrowu[idx] = 0u;
    }

    __shared__ unsigned lds[512 * 9];  // [c][w4(8)] packed bytes, +1 pad

#pragma unroll
    for (int it = 0; it < 16; ++it) {
        int idx = it * 256 + t;
        int c = idx >> 3, f4 = idx & 7;
        float4 v = x4[((size_t)bb * 512 + c) * 256 + h * 8 + f4];
        float A = A1[c] * inv_sact, B = B1[c] * inv_sact;
        unsigned q0 = (unsigned)(int)fminf(rintf(fmaxf(fmaf(v.x, A, B), 0.f)), 127.f);
        unsigned q1 = (unsigned)(int)fminf(rintf(fmaxf(fmaf(v.y, A, B), 0.f)), 127.f);
        unsigned q2 = (unsigned)(int)fminf(rintf(fmaxf(fmaf(v.z, A, B), 0.f)), 127.f);
        unsigned q3 = (unsigned)(int)fminf(rintf(fmaxf(fmaf(v.w, A, B), 0.f)), 127.f);
        lds[c * 9 + f4] = q0 | (q1 << 8) | (q2 << 16) | (q3 << 24);
    }
    __syncthreads();

#pragma unroll
    for (int it = 0; it < 4; ++it) {
        int p = it * 8 + (t >> 5);   // 0..31 = ci*4+cq
        int s = (t >> 2) & 7;        // w4 group
        int k = t & 3;               // w = s*4+k, w' = w+1
        unsigned L[16];
#pragma unroll
        for (int j = 0; j < 16; ++j) L[j] = lds[(p * 16 + j) * 9 + s];
        uint4 o;
        unsigned* op = (unsigned*)&o;
#pragma unroll
        for (int d = 0; d < 4; ++d)
            op[d] = ((L[4 * d] >> (8 * k)) & 255u) |
                    (((L[4 * d + 1] >> (8 * k)) & 255u) << 8) |
                    (((L[4 * d + 2] >> (8 * k)) & 255u) << 16) |
                    (((L[4 * d + 3] >> (8 * k)) & 255u) << 24);
        *(uint4*)(x2u + rowd + (size_t)(p * 34 + s * 4 + 1 + k) * 4) = o;
    }
}

// ---- kernel 3: int8 3x3 conv, dbuf B, vmcnt-ordered + kh-pipelined ---------
// block = 4 rows x 64 co, 4 waves = (rp row-pair, wh w-half);
// wave = 2 rows x 16 w x 64 co, acc[2][4] (r = row, nt = co-16-group).
// Per K-iter issue order (vmcnt retires in issue order!):
//   A-loads x12 -> B0,B1 ds_reads -> stage16 x9 (next buf) ->
//   MFMA kh0 (A-wait = vmcnt(9): stages stay in flight) -> B2 ds_reads ->
//   MFMA kh1 -> MFMA kh2 -> ONE __syncthreads (drains stages, had full iter).
// ds_reads of kh+1 overlap the MFMA cluster of kh (in-wave ILP).
// LDS 2x36KB=72KB -> 2 blocks/CU, 8 waves/CU.
__global__ __launch_bounds__(256, 2) void k_conv(
    const unsigned char* __restrict__ x2, const unsigned char* __restrict__ zrow,
    const signed char* __restrict__ wq,
    const float* __restrict__ wsc, const float* __restrict__ ws_f,
    unsigned* __restrict__ amaxy, float* __restrict__ y) {
    __shared__ char ldsb[73728];
    int t = threadIdx.x;
    int lane = t & 63, wv = t >> 6;
    int wh = wv & 1, rp = wv >> 1;   // w-half, row-pair
    int m = lane & 15, quad = lane >> 4;

    int bid = blockIdx.x;
    int tile = (bid & 7) * 64 + (bid >> 3);  // XCD swizzle, 64 tiles/XCD
    int ch = tile & 1;
    int rg = (tile >> 1) & 7;                // row-group of 4 rows
    int bb = tile >> 4;
    int co0 = ch * 64;
    int h0 = rg * 4 + rp * 2;                // this wave's first output row

    const unsigned char* xb = x2 + (size_t)bb * (32 * 17408);
    const v4i* rpt[4];
#pragma unroll
    for (int j = 0; j < 4; ++j) {
        int row = h0 - 1 + j;
        rpt[j] = (const v4i*)(((unsigned)row < 32u) ? (xb + (size_t)row * 17408) : zrow);
    }

    v4i acc[2][4];
#pragma unroll
    for (int i = 0; i < 2; ++i)
#pragma unroll
        for (int j = 0; j < 4; ++j) acc[i][j] = (v4i){0, 0, 0, 0};

    int abase = quad * 34 + m + wh * 16;  // [cq=quad][w'=m+wh*16] in v4i units

    // prologue: stage ci=0 into buffer 0 (36 x 1KB chunks, 9 per wave)
#pragma unroll
    for (int i = 0; i < 9; ++i) {
        int c = wv * 9 + i;
        int tap = c >> 2, cq = c & 3;
        const char* g = (const char*)wq +
            ((((size_t)(tap * 8 + 0) * 4 + cq) * 128 + co0) * 16) + lane * 16;
        stage16(g, ldsb + (c << 10), lane);
    }
    __syncthreads();

#pragma unroll
    for (int ci = 0; ci < 8; ++ci) {
        const v4i* bv = (const v4i*)(ldsb + (ci & 1) * 36864);

        // (1) A-loads FIRST: 12 global loads occupy the oldest vmcnt slots,
        // so the pre-MFMA A-wait is vmcnt(9) and leaves stages in flight.
        v4i A[4][3];
#pragma unroll
        for (int r = 0; r < 4; ++r)
#pragma unroll
            for (int kw = 0; kw < 3; ++kw)
                A[r][kw] = rpt[r][ci * 136 + abase + kw];

        auto load_B = [&](v4i(&B)[3][4], int kh) {
#pragma unroll
            for (int kw = 0; kw < 3; ++kw)
#pragma unroll
                for (int nt = 0; nt < 4; ++nt)
                    B[kw][nt] = bv[((kh * 3 + kw) * 4 + quad) * 64 + nt * 16 + m];
        };
        auto mfma_kh = [&](const v4i(&Ar0)[3], const v4i(&Ar1)[3],
                           const v4i(&B)[3][4]) {
            __builtin_amdgcn_s_setprio(1);
#pragma unroll
            for (int kw = 0; kw < 3; ++kw)
#pragma unroll
                for (int nt = 0; nt < 4; ++nt) {
                    acc[0][nt] = __builtin_amdgcn_mfma_i32_16x16x64_i8(
                        Ar0[kw], B[kw][nt], acc[0][nt], 0, 0, 0);
                    acc[1][nt] = __builtin_amdgcn_mfma_i32_16x16x64_i8(
                        Ar1[kw], B[kw][nt], acc[1][nt], 0, 0, 0);
                }
            __builtin_amdgcn_s_setprio(0);
        };

        // (2) B0 + B1 ds_reads up front (kh-pipeline depth 1)
        v4i B0[3][4], B1[3][4], B2[3][4];
        load_B(B0, 0);
        load_B(B1, 1);

        // (3) stage NEXT ci-group (9 global_load_lds) -- after A in vmcnt order
        if (ci < 7) {
#pragma unroll
            for (int i = 0; i < 9; ++i) {
                int c = wv * 9 + i;
                int tap = c >> 2, cq = c & 3;
                const char* g = (const char*)wq +
                    ((((size_t)(tap * 8 + ci + 1) * 4 + cq) * 128 + co0) * 16) + lane * 16;
                stage16(g, ldsb + ((ci + 1) & 1) * 36864 + (c << 10), lane);
            }
        }

        // (4..7) MFMA kh0 | issue B2 | MFMA kh1 | MFMA kh2
        mfma_kh(A[0], A[1], B0);
        load_B(B2, 2);
        mfma_kh(A[1], A[2], B1);
        mfma_kh(A[2], A[3], B2);

        __syncthreads();  // cur reads done by all waves + next-buf stages drained
    }

    // epilogue: C layout col(lane&15)=co, row(quad*4+reg)=w-within-half.
    // y unquantized; track block absmax -> one atomicMax per block.
    float s_act = ws_f[3];
    float mx = 0.f;
#pragma unroll
    for (int nt = 0; nt < 4; ++nt) {
        int co = co0 + nt * 16 + m;
        float sf = s_act * wsc[co];
#pragma unroll
        for (int r = 0; r < 2; ++r) {
            int row = h0 + r;
            float* yb = y + ((size_t)(bb * 128 + co)) * 1024 + row * 32 + wh * 16;
            float4 vv;
            vv.x = (float)acc[r][nt][0] * sf;
            vv.y = (float)acc[r][nt][1] * sf;
            vv.z = (float)acc[r][nt][2] * sf;
            vv.w = (float)acc[r][nt][3] * sf;
            *(float4*)(yb + quad * 4) = vv;
            mx = fmaxf(mx, fmaxf(fmaxf(fabsf(vv.x), fabsf(vv.y)),
                                 fmaxf(fabsf(vv.z), fabsf(vv.w))));
        }
    }
    mx = wave_max(mx);
    if (lane == 0) ((float*)ldsb)[wv] = mx;   // loop ended with __syncthreads
    __syncthreads();
    if (t == 0) {
        float* r = (float*)ldsb;
        float M = fmaxf(fmaxf(r[0], r[1]), fmaxf(r[2], r[3]));
        atomicMax(amaxy, __float_as_uint(M));
    }
}

// ---- kernel 4: final requant in place + write s_out -----------------------
__global__ __launch_bounds__(256) void k_yquant(float* __restrict__ yout,
                                                const unsigned* __restrict__ ws_u) {
    float s_out = __uint_as_float(ws_u[1]) / 127.0f;
    float4* y4 = (float4*)yout;
    int stride = gridDim.x * blockDim.x;
    for (int i = blockIdx.x * blockDim.x + threadIdx.x; i < 1048576; i += stride) {
        float4 v = y4[i];
        v.x = fminf(fmaxf(rintf(v.x / s_out), -128.f), 127.f) * s_out;
        v.y = fminf(fmaxf(rintf(v.y / s_out), -128.f), 127.f) * s_out;
        v.z = fminf(fmaxf(rintf(v.z / s_out), -128.f), 127.f) * s_out;
        v.w = fminf(fmaxf(rintf(v.w / s_out), -128.f), 127.f) * s_out;
        y4[i] = v;
    }
    if (blockIdx.x == 0 && threadIdx.x == 0) yout[4194304] = s_out;
}

extern "C" void kernel_launch(void* const* d_in, const int* in_sizes, int n_in,
                              void* d_out, int out_size, void* d_ws, size_t ws_size,
                              hipStream_t stream) {
    const float* x     = (const float*)d_in[0];
    const float* asf   = (const float*)d_in[1];
    const float* gamma = (const float*)d_in[2];
    const float* beta  = (const float*)d_in[3];
    const float* mean  = (const float*)d_in[4];
    const float* var   = (const float*)d_in[5];
    const float* cw    = (const float*)d_in[6];

    float*    ws_f = (float*)d_ws;
    unsigned* ws_u = (unsigned*)d_ws;
    signed char*   wq   = (signed char*)d_ws + WS_WQ;
    unsigned char* x2   = (unsigned char*)d_ws + WS_X2;
    unsigned char* zrow = (unsigned char*)d_ws + WS_ZROW;
    float* y = (float*)d_out;

    k_prep<<<641, 512, 0, stream>>>(gamma, beta, mean, var, asf, cw,
                                    (const float4*)x, ws_f, ws_u,
                                    ws_f + WS_WSC / 4, wq);
    k_xquant<<<1024, 256, 0, stream>>>((const float4*)x, ws_f,
                                       (unsigned*)x2, (unsigned*)zrow);
    k_conv<<<512, 256, 0, stream>>>(x2, zrow, wq, ws_f + WS_WSC / 4,
                                    ws_f, ws_u + 1, y);
    k_yquant<<<1024, 256, 0, stream>>>(y, ws_u);
}